// Round 3
// baseline (404.831 us; speedup 1.0000x reference)
//
#include <hip/hip_runtime.h>

typedef unsigned short u16;
typedef unsigned int u32;
typedef __attribute__((ext_vector_type(4))) float f32x4;
typedef __bf16 bf16x8 __attribute__((ext_vector_type(8)));

#define DI __device__ __forceinline__

DI u16 f2bf(float f) { return __builtin_bit_cast(u16, (__bf16)f); }
DI float bf2f(u16 h) {
  unsigned u = ((unsigned)h) << 16;
  return __builtin_bit_cast(float, u);
}
DI u32 pk2(float a, float b) {
  return (u32)__builtin_bit_cast(u16, (__bf16)a) |
         ((u32)__builtin_bit_cast(u16, (__bf16)b) << 16);
}
DI f32x4 mfma16(bf16x8 a, bf16x8 b, f32x4 c) {
  return __builtin_amdgcn_mfma_f32_16x16x32_bf16(a, b, c, 0, 0, 0);
}
DI void gload_lds16(const void* g, void* l) {
  __builtin_amdgcn_global_load_lds(
      (const __attribute__((address_space(1))) u32*)g,
      (__attribute__((address_space(3))) u32*)l, 16, 0, 0);
}

// Problem constants: B=16 T=12 N=512 D=96 G=4 S=10 K_T=3
// hTt layout: [b][s][d][m] with m = k*512+n   (160*96*1536 bf16)
// cat layout: [b][s][n][c], c in [0,480)      (81920*480 bf16)

// ---------------- K1: h = relu(Xw @ Wu^T), write hTt transposed -------------
// grid 3840 = 160(b,s) * 8(n-tile 64) * 3(k). block 256 (4 waves).
__global__ __launch_bounds__(256) void k1(const float* __restrict__ X,
                                          const float* __restrict__ Wu,
                                          u16* __restrict__ hTt) {
  __shared__ u16 As[64 * 296];   // Xw tile [n=64][c=288] (+8 pad)
  __shared__ u16 Bs[96 * 296];   // Wu rows [j=96][c=288]
  __shared__ u16 Ts[64 * 100];   // transpose buffer [n][d]
  const int wg = blockIdx.x;
  const int kk = wg % 3;
  const int n0 = ((wg / 3) & 7) * 64;
  const int bs = wg / 24;
  const int b = bs / 10, s = bs % 10;
  const int tid = threadIdx.x;

#pragma unroll
  for (int i = 0; i < 18; ++i) {
    int idx = tid + i * 256;          // < 4608 = 64*72
    int r = idx / 72, q = idx % 72;
    int kq = q / 24, dq = q % 24;
    const float4 v = *reinterpret_cast<const float4*>(
        &X[(((b * 12) + s + kq) * 512 + (n0 + r)) * 96 + dq * 4]);
    uint2 u; u.x = pk2(v.x, v.y); u.y = pk2(v.z, v.w);
    *reinterpret_cast<uint2*>(&As[r * 296 + q * 4]) = u;
  }
#pragma unroll
  for (int i = 0; i < 27; ++i) {
    int idx = tid + i * 256;          // < 6912 = 96*72
    int j = idx / 72, q = idx % 72;
    const float4 v = *reinterpret_cast<const float4*>(
        &Wu[(kk * 96 + j) * 288 + q * 4]);
    uint2 u; u.x = pk2(v.x, v.y); u.y = pk2(v.z, v.w);
    *reinterpret_cast<uint2*>(&Bs[j * 296 + q * 4]) = u;
  }
  __syncthreads();

  const int w = tid >> 6, l = tid & 63;
  const int lr = l & 15, lk = (l >> 4) * 8;
  f32x4 acc[6] = {};
#pragma unroll
  for (int ks = 0; ks < 9; ++ks) {
    bf16x8 a = *reinterpret_cast<const bf16x8*>(&As[(w * 16 + lr) * 296 + ks * 32 + lk]);
#pragma unroll
    for (int ct = 0; ct < 6; ++ct) {
      bf16x8 bb = *reinterpret_cast<const bf16x8*>(&Bs[(ct * 16 + lr) * 296 + ks * 32 + lk]);
      acc[ct] = mfma16(a, bb, acc[ct]);
    }
  }
  const int rowb = w * 16 + (l >> 4) * 4;
#pragma unroll
  for (int ct = 0; ct < 6; ++ct) {
#pragma unroll
    for (int rg = 0; rg < 4; ++rg) {
      float v = acc[ct][rg];
      v = v > 0.f ? v : 0.f;
      Ts[(rowb + rg) * 100 + ct * 16 + lr] = f2bf(v);
    }
  }
  __syncthreads();
  const int obase = bs * 96 * 1536 + kk * 512 + n0;
#pragma unroll
  for (int i = 0; i < 24; ++i) {
    int idx = tid + i * 256;          // < 6144 = 96*64
    int d = idx >> 6, n = idx & 63;
    hTt[obase + d * 1536 + n] = Ts[n * 100 + d];
  }
}

// ---------------- K1b: X0 = mean_k h -> cat[...,0:96] ----------------------
__global__ __launch_bounds__(256) void k1b(const u16* __restrict__ hTt,
                                           u16* __restrict__ cat) {
  __shared__ u16 Ss[128 * 100];  // [n][d]
  const int wg = blockIdx.x;
  const int nc = (wg & 3) * 128;
  const int bs = wg >> 2;
  const int tid = threadIdx.x;
#pragma unroll
  for (int j = 0; j < 6; ++j) {
    int o = tid + j * 256;            // < 1536 = 96*16
    int d = o >> 4, oc = o & 15;
    float a8[8] = {0.f, 0.f, 0.f, 0.f, 0.f, 0.f, 0.f, 0.f};
#pragma unroll
    for (int k = 0; k < 3; ++k) {
      const uint4 v = *reinterpret_cast<const uint4*>(
          &hTt[(bs * 96 + d) * 1536 + k * 512 + nc + oc * 8]);
      a8[0] += bf2f((u16)(v.x & 0xffffu)); a8[1] += bf2f((u16)(v.x >> 16));
      a8[2] += bf2f((u16)(v.y & 0xffffu)); a8[3] += bf2f((u16)(v.y >> 16));
      a8[4] += bf2f((u16)(v.z & 0xffffu)); a8[5] += bf2f((u16)(v.z >> 16));
      a8[6] += bf2f((u16)(v.w & 0xffffu)); a8[7] += bf2f((u16)(v.w >> 16));
    }
#pragma unroll
    for (int e = 0; e < 8; ++e)
      Ss[(oc * 8 + e) * 100 + d] = f2bf(a8[e] * (1.f / 3.f));
  }
  __syncthreads();
  const long ob = ((long)bs * 512 + nc) * 480;
#pragma unroll
  for (int i = 0; i < 48; ++i) {
    int idx = tid + i * 256;          // < 12288 = 128*96
    int n = idx / 96, d = idx % 96;
    cat[ob + n * 480 + d] = Ss[n * 100 + d];
  }
}

// ---------------- K2: Hk einsum -> cat[..., 96:480] ------------------------
// Per b: Out[(g,n),(s,d)] = sum_m dyn[g,b,n,m] * hTt[b,s,d,m]
// Block 256(rows: g,n0) x 192(cols: 2s x 96d), BK=64, 24 K-steps.
// 8 waves (4 wm x 2 wn), wave tile 64x96 (acc 4x6). 1 block/CU (136KB LDS).
// B: tri-buffered global_load_lds (3 issues/wave/step), pre-swizzled source.
// A: reg-staged fp32->bf16 (8 dwordx4 + cvt_pk), double-buffered LDS.
// Counted-vmcnt raw barriers: loop never drains vmcnt to 0 (B(t+2) in flight).
__global__ __launch_bounds__(512, 2) void k2(const float* __restrict__ dyn,
                                             const u16* __restrict__ hTt,
                                             u16* __restrict__ cat) {
  __shared__ u16 As[2][256 * 64];   // 64 KB, swizzled: elem ^ ((row&7)<<3)
  __shared__ u16 Bs[3][192 * 64];   // 72 KB, same swizzle via source
  const int wg0 = blockIdx.x;
  const int wg = (wg0 & 7) * 80 + (wg0 >> 3);   // bijective XCD swizzle (640%8==0)
  const int b = wg / 40;
  const int rem = wg % 40;
  const int rt = rem / 5, sp = rem % 5;
  const int g = rt >> 1, n0 = (rt & 1) * 256;
  const int tid = threadIdx.x;
  const int w = tid >> 6, l = tid & 63;
  const int wm = w & 3, wn = w >> 2;
  const int lr = l & 15, q = l >> 4;
  const int sw = (lr & 7) << 3;
  const long abase = (long)((g * 16 + b) * 512 + n0) * 1536;
  const long bbase = (long)((b * 10 + sp * 2) * 96) * 1536;

  // A staging: 256 rows x 64 K-cols fp32; thread: row=tid>>1, 32-col half.
  const int ar = tid >> 1, ah = (tid & 1) * 32;
  const float* aptr = &dyn[abase + (long)ar * 1536 + ah];
  const int ars = (ar & 7) << 3;
  float4 ald[8];

  // B staging: 24 wave-issues of 1KB; wave w does 3. Pre-swizzled source col.
  const int brow = tid >> 3;
  const int bcol = ((tid & 7) ^ (brow & 7)) * 8;

  f32x4 acc[4][6] = {};

  auto loadA = [&](int t) {
    const float* p = aptr + t * 64;
#pragma unroll
    for (int i = 0; i < 8; ++i) ald[i] = *reinterpret_cast<const float4*>(p + i * 4);
  };
  auto writeA = [&](int buf) {
    u16* dst = &As[buf][ar * 64];
#pragma unroll
    for (int i = 0; i < 4; ++i) {
      uint4 v;
      v.x = pk2(ald[2 * i].x, ald[2 * i].y);
      v.y = pk2(ald[2 * i].z, ald[2 * i].w);
      v.z = pk2(ald[2 * i + 1].x, ald[2 * i + 1].y);
      v.w = pk2(ald[2 * i + 1].z, ald[2 * i + 1].w);
      *reinterpret_cast<uint4*>(&dst[(ah + i * 8) ^ ars]) = v;
    }
  };
  auto issueB = [&](int t, int buf) {
#pragma unroll
    for (int j = 0; j < 3; ++j) {
      const u16* src = &hTt[bbase + (long)(j * 64 + brow) * 1536 + t * 64 + bcol];
      u16* dst = &Bs[buf][j * 4096 + w * 512];   // wave-uniform base, linear dest
      gload_lds16(src, dst);
    }
  };
  auto compute = [&](const u16* Ab, const u16* Bb) {
    __builtin_amdgcn_s_setprio(1);
#pragma unroll
    for (int ks = 0; ks < 2; ++ks) {
      const int ko = (ks * 32 + q * 8) ^ sw;
      bf16x8 a0 = *reinterpret_cast<const bf16x8*>(&Ab[(wm * 64 +  0 + lr) * 64 + ko]);
      bf16x8 a1 = *reinterpret_cast<const bf16x8*>(&Ab[(wm * 64 + 16 + lr) * 64 + ko]);
      bf16x8 a2 = *reinterpret_cast<const bf16x8*>(&Ab[(wm * 64 + 32 + lr) * 64 + ko]);
      bf16x8 a3 = *reinterpret_cast<const bf16x8*>(&Ab[(wm * 64 + 48 + lr) * 64 + ko]);
#pragma unroll
      for (int ct = 0; ct < 6; ++ct) {
        bf16x8 bb = *reinterpret_cast<const bf16x8*>(&Bb[(wn * 96 + ct * 16 + lr) * 64 + ko]);
        acc[0][ct] = mfma16(a0, bb, acc[0][ct]);
        acc[1][ct] = mfma16(a1, bb, acc[1][ct]);
        acc[2][ct] = mfma16(a2, bb, acc[2][ct]);
        acc[3][ct] = mfma16(a3, bb, acc[3][ct]);
      }
    }
    __builtin_amdgcn_s_setprio(0);
  };

  // Prologue: A(0)x8, B(0)x3, B(1)x3 in flight.
  loadA(0);
  asm volatile("" ::: "memory");   // keep A-loads issued before B gloadlds
  issueB(0, 0);
  issueB(1, 1);
  writeA(0);   // compiler waits A-loads (vmcnt 6), leaves B(0),B(1) in flight
  asm volatile("s_waitcnt vmcnt(3)\n\ts_waitcnt lgkmcnt(0)\n\ts_barrier" ::: "memory");

  int bi = 0;                                   // = t % 3
  for (int t = 0; t < 24; ++t) {
    if (t < 23) { loadA(t + 1); asm volatile("" ::: "memory"); }
    if (t < 22) { int b2 = bi + 2; if (b2 >= 3) b2 -= 3; issueB(t + 2, b2); }
    compute(As[t & 1], Bs[bi]);
    if (t < 23) {
      if (t < 22) asm volatile("s_waitcnt vmcnt(3)" ::: "memory");  // A done, B(t+1) done, B(t+2) in flight
      else        asm volatile("s_waitcnt vmcnt(0)" ::: "memory");  // tail
      writeA((t + 1) & 1);
      asm volatile("s_waitcnt lgkmcnt(0)\n\ts_barrier" ::: "memory");
    }
    ++bi; if (bi >= 3) bi = 0;
  }

  // Epilogue: cat[b, sp*2+wn, n0+wm*64+row, 96 + g*96 + d]
  const long cb = (long)((b * 10 + sp * 2 + wn) * 512 + n0 + wm * 64) * 480 + 96 + g * 96;
#pragma unroll
  for (int fr = 0; fr < 4; ++fr) {
#pragma unroll
    for (int ct = 0; ct < 6; ++ct) {
      const int d = ct * 16 + lr;
#pragma unroll
      for (int rg = 0; rg < 4; ++rg) {
        const int row = fr * 16 + q * 4 + rg;
        cat[cb + (long)row * 480 + d] = f2bf(acc[fr][ct][rg]);
      }
    }
  }
}

// ---------------- K3: out = cat @ Wg^T + bias -------------------------------
__global__ __launch_bounds__(256) void k3(const u16* __restrict__ cat,
                                          const float* __restrict__ Wg,
                                          const float* __restrict__ bias,
                                          float* __restrict__ out) {
  __shared__ u16 As[128 * 104];  // cat tile [r=128][c=96] (+8 pad)
  __shared__ u16 Bs[96 * 104];   // Wg rows  [do=96][c=96]
  const int row0 = blockIdx.x * 128;
  const int tid = threadIdx.x;
  const int w = tid >> 6, l = tid & 63;
  const int lr = l & 15, lk = (l >> 4) * 8;
  f32x4 acc[2][6] = {};

  for (int c0 = 0; c0 < 480; c0 += 96) {
#pragma unroll
    for (int i = 0; i < 12; ++i) {
      int idx = tid + i * 256;        // < 3072 = 128*24
      int r = idx / 24, q = idx % 24;
      const ushort4 v = *reinterpret_cast<const ushort4*>(
          &cat[(long)(row0 + r) * 480 + c0 + q * 4]);
      *reinterpret_cast<ushort4*>(&As[r * 104 + q * 4]) = v;
    }
#pragma unroll
    for (int i = 0; i < 9; ++i) {
      int idx = tid + i * 256;        // < 2304 = 96*24
      int j = idx / 24, q = idx % 24;
      const float4 v = *reinterpret_cast<const float4*>(&Wg[j * 480 + c0 + q * 4]);
      uint2 u; u.x = pk2(v.x, v.y); u.y = pk2(v.z, v.w);
      *reinterpret_cast<uint2*>(&Bs[j * 104 + q * 4]) = u;
    }
    __syncthreads();
#pragma unroll
    for (int ks = 0; ks < 3; ++ks) {
      bf16x8 a0 = *reinterpret_cast<const bf16x8*>(&As[(w * 32 + lr) * 104 + ks * 32 + lk]);
      bf16x8 a1 = *reinterpret_cast<const bf16x8*>(&As[(w * 32 + 16 + lr) * 104 + ks * 32 + lk]);
#pragma unroll
      for (int ct = 0; ct < 6; ++ct) {
        bf16x8 bb = *reinterpret_cast<const bf16x8*>(&Bs[(ct * 16 + lr) * 104 + ks * 32 + lk]);
        acc[0][ct] = mfma16(a0, bb, acc[0][ct]);
        acc[1][ct] = mfma16(a1, bb, acc[1][ct]);
      }
    }
    __syncthreads();
  }
#pragma unroll
  for (int rt2 = 0; rt2 < 2; ++rt2) {
    const int r = row0 + w * 32 + rt2 * 16 + (l >> 4) * 4;
#pragma unroll
    for (int ct = 0; ct < 6; ++ct) {
      const int dd = ct * 16 + lr;
      const float bv = bias[dd];
#pragma unroll
      for (int rg = 0; rg < 4; ++rg)
        out[(long)(r + rg) * 96 + dd] = acc[rt2][ct][rg] + bv;
    }
  }
}

extern "C" void kernel_launch(void* const* d_in, const int* in_sizes, int n_in,
                              void* d_out, int out_size, void* d_ws, size_t ws_size,
                              hipStream_t stream) {
  const float* X    = (const float*)d_in[0];
  const float* dyn  = (const float*)d_in[1];
  const float* Wu   = (const float*)d_in[2];
  const float* Wg   = (const float*)d_in[3];
  const float* bias = (const float*)d_in[4];
  float* out = (float*)d_out;

  const size_t hTt_elems = (size_t)160 * 96 * 1536;   // 23,592,960
  const size_t cat_elems = (size_t)81920 * 480;       // 39,321,600
  if (ws_size < (hTt_elems + cat_elems) * sizeof(u16)) return;
  u16* hTt = (u16*)d_ws;
  u16* cat = hTt + hTt_elems;

  hipLaunchKernelGGL(k1,  dim3(3840), dim3(256), 0, stream, X, Wu, hTt);
  hipLaunchKernelGGL(k1b, dim3(640),  dim3(256), 0, stream, hTt, cat);
  hipLaunchKernelGGL(k2,  dim3(640),  dim3(512), 0, stream, dyn, hTt, cat);
  hipLaunchKernelGGL(k3,  dim3(640),  dim3(256), 0, stream, cat, Wg, bias, out);
}

// Round 4
// 397.430 us; speedup vs baseline: 1.0186x; 1.0186x over previous
//
#include <hip/hip_runtime.h>

typedef unsigned short u16;
typedef unsigned int u32;
typedef __attribute__((ext_vector_type(4))) float f32x4;
typedef __bf16 bf16x8 __attribute__((ext_vector_type(8)));

#define DI __device__ __forceinline__

DI u16 f2bf(float f) { return __builtin_bit_cast(u16, (__bf16)f); }
DI float bf2f(u16 h) {
  unsigned u = ((unsigned)h) << 16;
  return __builtin_bit_cast(float, u);
}
DI u32 pk2(float a, float b) {
  return (u32)__builtin_bit_cast(u16, (__bf16)a) |
         ((u32)__builtin_bit_cast(u16, (__bf16)b) << 16);
}
DI f32x4 mfma16(bf16x8 a, bf16x8 b, f32x4 c) {
  return __builtin_amdgcn_mfma_f32_16x16x32_bf16(a, b, c, 0, 0, 0);
}
DI void gload_lds16(const void* g, void* l) {
  __builtin_amdgcn_global_load_lds(
      (const __attribute__((address_space(1))) u32*)g,
      (__attribute__((address_space(3))) u32*)l, 16, 0, 0);
}

#define MEMB asm volatile("" ::: "memory")

// Problem constants: B=16 T=12 N=512 D=96 G=4 S=10 K_T=3
// hTt layout: [b][s][d][m] with m = k*512+n   (160*96*1536 bf16)
// cat layout: [b][s][n][c], c in [0,480)      (81920*480 bf16)

// ---------------- K1: h = relu(Xw @ Wu^T), write hTt transposed -------------
// grid 3840 = 160(b,s) * 8(n-tile 64) * 3(k). block 256 (4 waves).
__global__ __launch_bounds__(256) void k1(const float* __restrict__ X,
                                          const float* __restrict__ Wu,
                                          u16* __restrict__ hTt) {
  __shared__ u16 As[64 * 296];   // Xw tile [n=64][c=288] (+8 pad)
  __shared__ u16 Bs[96 * 296];   // Wu rows [j=96][c=288]
  __shared__ u16 Ts[64 * 100];   // transpose buffer [n][d]
  const int wg = blockIdx.x;
  const int kk = wg % 3;
  const int n0 = ((wg / 3) & 7) * 64;
  const int bs = wg / 24;
  const int b = bs / 10, s = bs % 10;
  const int tid = threadIdx.x;

#pragma unroll
  for (int i = 0; i < 18; ++i) {
    int idx = tid + i * 256;          // < 4608 = 64*72
    int r = idx / 72, q = idx % 72;
    int kq = q / 24, dq = q % 24;
    const float4 v = *reinterpret_cast<const float4*>(
        &X[(((b * 12) + s + kq) * 512 + (n0 + r)) * 96 + dq * 4]);
    uint2 u; u.x = pk2(v.x, v.y); u.y = pk2(v.z, v.w);
    *reinterpret_cast<uint2*>(&As[r * 296 + q * 4]) = u;
  }
#pragma unroll
  for (int i = 0; i < 27; ++i) {
    int idx = tid + i * 256;          // < 6912 = 96*72
    int j = idx / 72, q = idx % 72;
    const float4 v = *reinterpret_cast<const float4*>(
        &Wu[(kk * 96 + j) * 288 + q * 4]);
    uint2 u; u.x = pk2(v.x, v.y); u.y = pk2(v.z, v.w);
    *reinterpret_cast<uint2*>(&Bs[j * 296 + q * 4]) = u;
  }
  __syncthreads();

  const int w = tid >> 6, l = tid & 63;
  const int lr = l & 15, lk = (l >> 4) * 8;
  f32x4 acc[6] = {};
#pragma unroll
  for (int ks = 0; ks < 9; ++ks) {
    bf16x8 a = *reinterpret_cast<const bf16x8*>(&As[(w * 16 + lr) * 296 + ks * 32 + lk]);
#pragma unroll
    for (int ct = 0; ct < 6; ++ct) {
      bf16x8 bb = *reinterpret_cast<const bf16x8*>(&Bs[(ct * 16 + lr) * 296 + ks * 32 + lk]);
      acc[ct] = mfma16(a, bb, acc[ct]);
    }
  }
  const int rowb = w * 16 + (l >> 4) * 4;
#pragma unroll
  for (int ct = 0; ct < 6; ++ct) {
#pragma unroll
    for (int rg = 0; rg < 4; ++rg) {
      float v = acc[ct][rg];
      v = v > 0.f ? v : 0.f;
      Ts[(rowb + rg) * 100 + ct * 16 + lr] = f2bf(v);
    }
  }
  __syncthreads();
  const int obase = bs * 96 * 1536 + kk * 512 + n0;
#pragma unroll
  for (int i = 0; i < 24; ++i) {
    int idx = tid + i * 256;          // < 6144 = 96*64
    int d = idx >> 6, n = idx & 63;
    hTt[obase + d * 1536 + n] = Ts[n * 100 + d];
  }
}

// ---------------- K1b: X0 = mean_k h -> cat[...,0:96] ----------------------
__global__ __launch_bounds__(256) void k1b(const u16* __restrict__ hTt,
                                           u16* __restrict__ cat) {
  __shared__ u16 Ss[128 * 100];  // [n][d]
  const int wg = blockIdx.x;
  const int nc = (wg & 3) * 128;
  const int bs = wg >> 2;
  const int tid = threadIdx.x;
#pragma unroll
  for (int j = 0; j < 6; ++j) {
    int o = tid + j * 256;            // < 1536 = 96*16
    int d = o >> 4, oc = o & 15;
    float a8[8] = {0.f, 0.f, 0.f, 0.f, 0.f, 0.f, 0.f, 0.f};
#pragma unroll
    for (int k = 0; k < 3; ++k) {
      const uint4 v = *reinterpret_cast<const uint4*>(
          &hTt[(bs * 96 + d) * 1536 + k * 512 + nc + oc * 8]);
      a8[0] += bf2f((u16)(v.x & 0xffffu)); a8[1] += bf2f((u16)(v.x >> 16));
      a8[2] += bf2f((u16)(v.y & 0xffffu)); a8[3] += bf2f((u16)(v.y >> 16));
      a8[4] += bf2f((u16)(v.z & 0xffffu)); a8[5] += bf2f((u16)(v.z >> 16));
      a8[6] += bf2f((u16)(v.w & 0xffffu)); a8[7] += bf2f((u16)(v.w >> 16));
    }
#pragma unroll
    for (int e = 0; e < 8; ++e)
      Ss[(oc * 8 + e) * 100 + d] = f2bf(a8[e] * (1.f / 3.f));
  }
  __syncthreads();
  const long ob = ((long)bs * 512 + nc) * 480;
#pragma unroll
  for (int i = 0; i < 48; ++i) {
    int idx = tid + i * 256;          // < 12288 = 128*96
    int n = idx / 96, d = idx % 96;
    cat[ob + n * 480 + d] = Ss[n * 100 + d];
  }
}

// ---------------- K2: Hk einsum -> cat[..., 96:480] ------------------------
// Per b: Out[(g,n),(s,d)] = sum_m dyn[g,b,n,m] * hTt[b,s,d,m]
// Block 256(rows) x 192(cols), BK=64, 24 K-steps. 8 waves (4wm x 2wn),
// wave tile 64x96 (acc 4x6). 1 block/CU (136KB LDS).
// B: tri-buffered gload_lds; A: DOUBLE reg-buffered (aldA/aldB) + dbuf LDS.
// Both A(t+2)/B(t+2) issued at step t, waited end of step t+1 (vmcnt(11)):
// full step+compute of latency cover; loop never drains vmcnt to 0.
__global__ __launch_bounds__(512, 2) void k2(const float* __restrict__ dyn,
                                             const u16* __restrict__ hTt,
                                             u16* __restrict__ cat) {
  __shared__ u16 As[2][256 * 64];   // 64 KB, swizzled: elem ^ ((row&7)<<3)
  __shared__ u16 Bs[3][192 * 64];   // 72 KB, same swizzle via source
  const int wg0 = blockIdx.x;
  const int wg = (wg0 & 7) * 80 + (wg0 >> 3);   // bijective XCD swizzle (640%8==0)
  const int b = wg / 40;
  const int rem = wg % 40;
  const int rt = rem / 5, sp = rem % 5;
  const int g = rt >> 1, n0 = (rt & 1) * 256;
  const int tid = threadIdx.x;
  const int w = tid >> 6, l = tid & 63;
  const int wm = w & 3, wn = w >> 2;
  const int lr = l & 15, q = l >> 4;
  const int sw = (lr & 7) << 3;
  const long abase = (long)((g * 16 + b) * 512 + n0) * 1536;
  const long bbase = (long)((b * 10 + sp * 2) * 96) * 1536;

  // A staging: 256 rows x 64 K-cols fp32; thread: row=tid>>1, 32-col half.
  const int ar = tid >> 1, ah = (tid & 1) * 32;
  const float* aptr = &dyn[abase + (long)ar * 1536 + ah];
  const int ars = (ar & 7) << 3;
  float4 aldA[8], aldB[8];

  // B staging: wave w issues 3 gload_lds of 1KB; pre-swizzled source col.
  const int brow = tid >> 3;
  const int bcol = ((tid & 7) ^ (brow & 7)) * 8;

  f32x4 acc[4][6] = {};

  auto loadA = [&](int t, float4* ald) {
    const float* p = aptr + (long)t * 64;
#pragma unroll
    for (int i = 0; i < 8; ++i) ald[i] = *reinterpret_cast<const float4*>(p + i * 4);
  };
  auto writeA = [&](int buf, const float4* ald) {
    u16* dst = &As[buf][ar * 64];
#pragma unroll
    for (int i = 0; i < 4; ++i) {
      uint4 v;
      v.x = pk2(ald[2 * i].x, ald[2 * i].y);
      v.y = pk2(ald[2 * i].z, ald[2 * i].w);
      v.z = pk2(ald[2 * i + 1].x, ald[2 * i + 1].y);
      v.w = pk2(ald[2 * i + 1].z, ald[2 * i + 1].w);
      *reinterpret_cast<uint4*>(&dst[(ah + i * 8) ^ ars]) = v;
    }
  };
  auto issueB = [&](int t, int buf) {
    u16* base = &Bs[0][0] + buf * 12288;
#pragma unroll
    for (int j = 0; j < 3; ++j) {
      const u16* src = &hTt[bbase + (long)(j * 64 + brow) * 1536 + t * 64 + bcol];
      gload_lds16(src, base + j * 4096 + w * 512);   // wave-uniform dest
    }
  };
  auto compute = [&](const u16* Ab, const u16* Bb) {
    __builtin_amdgcn_s_setprio(1);
#pragma unroll
    for (int ks = 0; ks < 2; ++ks) {
      const int ko = (ks * 32 + q * 8) ^ sw;
      bf16x8 a0 = *reinterpret_cast<const bf16x8*>(&Ab[(wm * 64 +  0 + lr) * 64 + ko]);
      bf16x8 a1 = *reinterpret_cast<const bf16x8*>(&Ab[(wm * 64 + 16 + lr) * 64 + ko]);
      bf16x8 a2 = *reinterpret_cast<const bf16x8*>(&Ab[(wm * 64 + 32 + lr) * 64 + ko]);
      bf16x8 a3 = *reinterpret_cast<const bf16x8*>(&Ab[(wm * 64 + 48 + lr) * 64 + ko]);
#pragma unroll
      for (int ct = 0; ct < 6; ++ct) {
        bf16x8 bb = *reinterpret_cast<const bf16x8*>(&Bb[(wn * 96 + ct * 16 + lr) * 64 + ko]);
        acc[0][ct] = mfma16(a0, bb, acc[0][ct]);
        acc[1][ct] = mfma16(a1, bb, acc[1][ct]);
        acc[2][ct] = mfma16(a2, bb, acc[2][ct]);
        acc[3][ct] = mfma16(a3, bb, acc[3][ct]);
      }
    }
    __builtin_amdgcn_s_setprio(0);
  };

  // Prologue. Issue order: A0(8), B0(3), A1(8), B1(3). writeA auto-waits A0;
  // vmcnt(11) forces B0 done, leaves A1+B1=11 in flight across the barrier.
  loadA(0, aldA); MEMB;
  issueB(0, 0);   MEMB;
  loadA(1, aldB); MEMB;
  issueB(1, 1);
  writeA(0, aldA);
  asm volatile("s_waitcnt vmcnt(11)\n\ts_waitcnt lgkmcnt(0)\n\ts_barrier" ::: "memory");

  // Steady state: steps 0..21 (tt pairs). At step t: issue A(t+2) into reg-set
  // (t&1), issue B(t+2) into buf (t+2)%3; compute tile t; vmcnt(11) completes
  // A(t+1),B(t+1); writeA tile t+1 into As[(t+1)&1]; barrier.
  int bi = 0;  // = t0 % 3
#pragma unroll 1
  for (int tt = 0; tt < 11; ++tt) {
    const int t0 = 2 * tt;
    {  // even step: loads into aldA, write from aldB
      loadA(t0 + 2, aldA); MEMB;
      { int ib = bi + 2; if (ib >= 3) ib -= 3; issueB(t0 + 2, ib); }
      compute(As[0], &Bs[0][0] + bi * 12288);
      asm volatile("s_waitcnt vmcnt(11)" ::: "memory");
      writeA(1, aldB);
      asm volatile("s_waitcnt lgkmcnt(0)\n\ts_barrier" ::: "memory");
    }
    ++bi; if (bi >= 3) bi = 0;
    const int t1 = t0 + 1;
    {  // odd step: loads into aldB, write from aldA
      loadA(t1 + 2, aldB); MEMB;
      { int ib = bi + 2; if (ib >= 3) ib -= 3; issueB(t1 + 2, ib); }
      compute(As[1], &Bs[0][0] + bi * 12288);
      asm volatile("s_waitcnt vmcnt(11)" ::: "memory");
      writeA(0, aldA);
      asm volatile("s_waitcnt lgkmcnt(0)\n\ts_barrier" ::: "memory");
    }
    ++bi; if (bi >= 3) bi = 0;
  }
  // Tail: t=22 (bi=1), t=23 (bi=2). aldB holds tile 23 (loaded at step 21).
  compute(As[0], &Bs[0][0] + 1 * 12288);
  asm volatile("s_waitcnt vmcnt(0)" ::: "memory");
  writeA(1, aldB);
  asm volatile("s_waitcnt lgkmcnt(0)\n\ts_barrier" ::: "memory");
  compute(As[1], &Bs[0][0] + 2 * 12288);

  // Epilogue: cat[b, sp*2+wn, n0+wm*64+row, 96 + g*96 + d]
  const long cb = (long)((b * 10 + sp * 2 + wn) * 512 + n0 + wm * 64) * 480 + 96 + g * 96;
#pragma unroll
  for (int fr = 0; fr < 4; ++fr) {
#pragma unroll
    for (int ct = 0; ct < 6; ++ct) {
      const int d = ct * 16 + lr;
#pragma unroll
      for (int rg = 0; rg < 4; ++rg) {
        const int row = fr * 16 + q * 4 + rg;
        cat[cb + (long)row * 480 + d] = f2bf(acc[fr][ct][rg]);
      }
    }
  }
}

// ---------------- K3: out = cat @ Wg^T + bias -------------------------------
__global__ __launch_bounds__(256) void k3(const u16* __restrict__ cat,
                                          const float* __restrict__ Wg,
                                          const float* __restrict__ bias,
                                          float* __restrict__ out) {
  __shared__ u16 As[128 * 104];  // cat tile [r=128][c=96] (+8 pad)
  __shared__ u16 Bs[96 * 104];   // Wg rows  [do=96][c=96]
  const int row0 = blockIdx.x * 128;
  const int tid = threadIdx.x;
  const int w = tid >> 6, l = tid & 63;
  const int lr = l & 15, lk = (l >> 4) * 8;
  f32x4 acc[2][6] = {};

  for (int c0 = 0; c0 < 480; c0 += 96) {
#pragma unroll
    for (int i = 0; i < 12; ++i) {
      int idx = tid + i * 256;        // < 3072 = 128*24
      int r = idx / 24, q = idx % 24;
      const ushort4 v = *reinterpret_cast<const ushort4*>(
          &cat[(long)(row0 + r) * 480 + c0 + q * 4]);
      *reinterpret_cast<ushort4*>(&As[r * 104 + q * 4]) = v;
    }
#pragma unroll
    for (int i = 0; i < 9; ++i) {
      int idx = tid + i * 256;        // < 2304 = 96*24
      int j = idx / 24, q = idx % 24;
      const float4 v = *reinterpret_cast<const float4*>(&Wg[j * 480 + c0 + q * 4]);
      uint2 u; u.x = pk2(v.x, v.y); u.y = pk2(v.z, v.w);
      *reinterpret_cast<uint2*>(&Bs[j * 104 + q * 4]) = u;
    }
    __syncthreads();
#pragma unroll
    for (int ks = 0; ks < 3; ++ks) {
      bf16x8 a0 = *reinterpret_cast<const bf16x8*>(&As[(w * 32 + lr) * 104 + ks * 32 + lk]);
      bf16x8 a1 = *reinterpret_cast<const bf16x8*>(&As[(w * 32 + 16 + lr) * 104 + ks * 32 + lk]);
#pragma unroll
      for (int ct = 0; ct < 6; ++ct) {
        bf16x8 bb = *reinterpret_cast<const bf16x8*>(&Bs[(ct * 16 + lr) * 104 + ks * 32 + lk]);
        acc[0][ct] = mfma16(a0, bb, acc[0][ct]);
        acc[1][ct] = mfma16(a1, bb, acc[1][ct]);
      }
    }
    __syncthreads();
  }
#pragma unroll
  for (int rt2 = 0; rt2 < 2; ++rt2) {
    const int r = row0 + w * 32 + rt2 * 16 + (l >> 4) * 4;
#pragma unroll
    for (int ct = 0; ct < 6; ++ct) {
      const int dd = ct * 16 + lr;
      const float bv = bias[dd];
#pragma unroll
      for (int rg = 0; rg < 4; ++rg)
        out[(long)(r + rg) * 96 + dd] = acc[rt2][ct][rg] + bv;
    }
  }
}

extern "C" void kernel_launch(void* const* d_in, const int* in_sizes, int n_in,
                              void* d_out, int out_size, void* d_ws, size_t ws_size,
                              hipStream_t stream) {
  const float* X    = (const float*)d_in[0];
  const float* dyn  = (const float*)d_in[1];
  const float* Wu   = (const float*)d_in[2];
  const float* Wg   = (const float*)d_in[3];
  const float* bias = (const float*)d_in[4];
  float* out = (float*)d_out;

  const size_t hTt_elems = (size_t)160 * 96 * 1536;   // 23,592,960
  const size_t cat_elems = (size_t)81920 * 480;       // 39,321,600
  if (ws_size < (hTt_elems + cat_elems) * sizeof(u16)) return;
  u16* hTt = (u16*)d_ws;
  u16* cat = hTt + hTt_elems;

  hipLaunchKernelGGL(k1,  dim3(3840), dim3(256), 0, stream, X, Wu, hTt);
  hipLaunchKernelGGL(k1b, dim3(640),  dim3(256), 0, stream, hTt, cat);
  hipLaunchKernelGGL(k2,  dim3(640),  dim3(512), 0, stream, dyn, hTt, cat);
  hipLaunchKernelGGL(k3,  dim3(640),  dim3(256), 0, stream, cat, Wg, bias, out);
}

// Round 5
// 319.715 us; speedup vs baseline: 1.2662x; 1.2431x over previous
//
#include <hip/hip_runtime.h>

typedef unsigned short u16;
typedef unsigned int u32;
typedef __attribute__((ext_vector_type(4))) float f32x4;
typedef __bf16 bf16x8 __attribute__((ext_vector_type(8)));

#define DI __device__ __forceinline__

DI u16 f2bf(float f) { return __builtin_bit_cast(u16, (__bf16)f); }
DI float bf2f(u16 h) {
  unsigned u = ((unsigned)h) << 16;
  return __builtin_bit_cast(float, u);
}
DI u32 pk2(float a, float b) {
  return (u32)__builtin_bit_cast(u16, (__bf16)a) |
         ((u32)__builtin_bit_cast(u16, (__bf16)b) << 16);
}
DI f32x4 mfma16(bf16x8 a, bf16x8 b, f32x4 c) {
  return __builtin_amdgcn_mfma_f32_16x16x32_bf16(a, b, c, 0, 0, 0);
}
DI void gload_lds16(const void* g, void* l) {
  __builtin_amdgcn_global_load_lds(
      (const __attribute__((address_space(1))) u32*)g,
      (__attribute__((address_space(3))) u32*)l, 16, 0, 0);
}

#define MEMB asm volatile("" ::: "memory")

// Problem constants: B=16 T=12 N=512 D=96 G=4 S=10 K_T=3
// hTt layout: [b][s][d][m] with m = k*512+n   (160*96*1536 bf16)
// cat layout: [b][s][n][c], c in [0,480)      (81920*480 bf16)

// ---------------- K1: h = relu(Xw @ Wu^T), write hTt transposed -------------
// grid 3840 = 160(b,s) * 8(n-tile 64) * 3(k). block 256 (4 waves).
__global__ __launch_bounds__(256) void k1(const float* __restrict__ X,
                                          const float* __restrict__ Wu,
                                          u16* __restrict__ hTt) {
  __shared__ u16 As[64 * 296];   // Xw tile [n=64][c=288] (+8 pad)
  __shared__ u16 Bs[96 * 296];   // Wu rows [j=96][c=288]
  __shared__ u16 Ts[64 * 100];   // transpose buffer [n][d]
  const int wg = blockIdx.x;
  const int kk = wg % 3;
  const int n0 = ((wg / 3) & 7) * 64;
  const int bs = wg / 24;
  const int b = bs / 10, s = bs % 10;
  const int tid = threadIdx.x;

#pragma unroll
  for (int i = 0; i < 18; ++i) {
    int idx = tid + i * 256;          // < 4608 = 64*72
    int r = idx / 72, q = idx % 72;
    int kq = q / 24, dq = q % 24;
    const float4 v = *reinterpret_cast<const float4*>(
        &X[(((b * 12) + s + kq) * 512 + (n0 + r)) * 96 + dq * 4]);
    uint2 u; u.x = pk2(v.x, v.y); u.y = pk2(v.z, v.w);
    *reinterpret_cast<uint2*>(&As[r * 296 + q * 4]) = u;
  }
#pragma unroll
  for (int i = 0; i < 27; ++i) {
    int idx = tid + i * 256;          // < 6912 = 96*72
    int j = idx / 72, q = idx % 72;
    const float4 v = *reinterpret_cast<const float4*>(
        &Wu[(kk * 96 + j) * 288 + q * 4]);
    uint2 u; u.x = pk2(v.x, v.y); u.y = pk2(v.z, v.w);
    *reinterpret_cast<uint2*>(&Bs[j * 296 + q * 4]) = u;
  }
  __syncthreads();

  const int w = tid >> 6, l = tid & 63;
  const int lr = l & 15, lk = (l >> 4) * 8;
  f32x4 acc[6] = {};
#pragma unroll
  for (int ks = 0; ks < 9; ++ks) {
    bf16x8 a = *reinterpret_cast<const bf16x8*>(&As[(w * 16 + lr) * 296 + ks * 32 + lk]);
#pragma unroll
    for (int ct = 0; ct < 6; ++ct) {
      bf16x8 bb = *reinterpret_cast<const bf16x8*>(&Bs[(ct * 16 + lr) * 296 + ks * 32 + lk]);
      acc[ct] = mfma16(a, bb, acc[ct]);
    }
  }
  const int rowb = w * 16 + (l >> 4) * 4;
#pragma unroll
  for (int ct = 0; ct < 6; ++ct) {
#pragma unroll
    for (int rg = 0; rg < 4; ++rg) {
      float v = acc[ct][rg];
      v = v > 0.f ? v : 0.f;
      Ts[(rowb + rg) * 100 + ct * 16 + lr] = f2bf(v);
    }
  }
  __syncthreads();
  const int obase = bs * 96 * 1536 + kk * 512 + n0;
#pragma unroll
  for (int i = 0; i < 24; ++i) {
    int idx = tid + i * 256;          // < 6144 = 96*64
    int d = idx >> 6, n = idx & 63;
    hTt[obase + d * 1536 + n] = Ts[n * 100 + d];
  }
}

// ---------------- K1b: X0 = mean_k h -> cat[...,0:96] ----------------------
__global__ __launch_bounds__(256) void k1b(const u16* __restrict__ hTt,
                                           u16* __restrict__ cat) {
  __shared__ u16 Ss[128 * 100];  // [n][d]
  const int wg = blockIdx.x;
  const int nc = (wg & 3) * 128;
  const int bs = wg >> 2;
  const int tid = threadIdx.x;
#pragma unroll
  for (int j = 0; j < 6; ++j) {
    int o = tid + j * 256;            // < 1536 = 96*16
    int d = o >> 4, oc = o & 15;
    float a8[8] = {0.f, 0.f, 0.f, 0.f, 0.f, 0.f, 0.f, 0.f};
#pragma unroll
    for (int k = 0; k < 3; ++k) {
      const uint4 v = *reinterpret_cast<const uint4*>(
          &hTt[(bs * 96 + d) * 1536 + k * 512 + nc + oc * 8]);
      a8[0] += bf2f((u16)(v.x & 0xffffu)); a8[1] += bf2f((u16)(v.x >> 16));
      a8[2] += bf2f((u16)(v.y & 0xffffu)); a8[3] += bf2f((u16)(v.y >> 16));
      a8[4] += bf2f((u16)(v.z & 0xffffu)); a8[5] += bf2f((u16)(v.z >> 16));
      a8[6] += bf2f((u16)(v.w & 0xffffu)); a8[7] += bf2f((u16)(v.w >> 16));
    }
#pragma unroll
    for (int e = 0; e < 8; ++e)
      Ss[(oc * 8 + e) * 100 + d] = f2bf(a8[e] * (1.f / 3.f));
  }
  __syncthreads();
  const long ob = ((long)bs * 512 + nc) * 480;
#pragma unroll
  for (int i = 0; i < 48; ++i) {
    int idx = tid + i * 256;          // < 12288 = 128*96
    int n = idx / 96, d = idx % 96;
    cat[ob + n * 480 + d] = Ss[n * 100 + d];
  }
}

// ---------------- K2: Hk einsum -> cat[..., 96:480] ------------------------
// Per b: Out[(g,n),(s,d)] = sum_m dyn[g,b,n,m] * hTt[b,s,d,m]
// Block tile 128(rows: one g, 128 n) x 192(cols: 2s x 96d), BK=64, 24 steps.
// 8 waves (4wm x 2wn), wave tile 32x96 (acc 2x6). LDS 80KB -> 2 blocks/CU.
// Simple 2-phase dbuf (prefetch-then-compute, __syncthreads drain); the
// co-resident block provides the latency cover (TLP) - R2 regime, leaner.
// XCD-group swizzle: the 20 blocks sharing (b,n0) [4g x 5sp] land on one XCD
// so dyn 5x and hTt 4x re-reads are L2-served (slices ~2MB < 4MB L2/XCD).
__global__ __launch_bounds__(512, 4) void k2(const float* __restrict__ dyn,
                                             const u16* __restrict__ hTt,
                                             u16* __restrict__ cat) {
  __shared__ u16 As[2][128 * 64];   // 16 KB each, swizzled: elem ^ ((row&7)<<3)
  __shared__ u16 Bs[2][192 * 64];   // 24 KB each, swizzle via pre-swizzled src
  const int bid = blockIdx.x;
  // bid -> (xcd = bid%8 assumed RR). Within XCD: 8 groups x 20 (g,sp) blocks.
  const int xcd = bid & 7, kk = bid >> 3;       // kk 0..159
  const int glocal = kk / 20, r20 = kk % 20;    // glocal 0..7
  const int g = r20 / 5, sp = r20 % 5;
  const int gi = glocal * 8 + xcd;              // group 0..63 = (b, n0i)
  const int b = gi >> 2, n0 = (gi & 3) * 128;

  const int tid = threadIdx.x;
  const int w = tid >> 6, l = tid & 63;
  const int wm = w & 3, wn = w >> 2;
  const int lr = l & 15, q = l >> 4;
  const int sw = (lr & 7) << 3;

  const long abase = (long)((g * 16 + b) * 512 + n0) * 1536;
  const long bbase = (long)((b * 10 + sp * 2) * 96) * 1536;

  // A staging: 128 rows x 64 K-cols fp32 = 32KB; thread: row=tid>>2, 16-col seg.
  const int ar = tid >> 2, seg = (tid & 3) * 16;
  const float* aptr = &dyn[abase + (long)ar * 1536 + seg];
  const int ars = (ar & 7) << 3;
  const int awo0 = ar * 64 + (seg ^ ars);
  const int awo1 = ar * 64 + ((seg + 8) ^ ars);

  // B staging: 3 gload_lds/wave (1KB each, 8 rows x 128B); pre-swizzled source.
  const int brow = tid >> 3;
  const int bcol = ((tid & 7) ^ (brow & 7)) * 8;

  f32x4 acc[2][6] = {};
  float4 ald[4];

  auto loadA = [&](int t) {
    const float* p = aptr + (long)t * 64;
#pragma unroll
    for (int i = 0; i < 4; ++i) ald[i] = *reinterpret_cast<const float4*>(p + i * 4);
  };
  auto writeA = [&](int buf) {
    uint4 v0, v1;
    v0.x = pk2(ald[0].x, ald[0].y); v0.y = pk2(ald[0].z, ald[0].w);
    v0.z = pk2(ald[1].x, ald[1].y); v0.w = pk2(ald[1].z, ald[1].w);
    v1.x = pk2(ald[2].x, ald[2].y); v1.y = pk2(ald[2].z, ald[2].w);
    v1.z = pk2(ald[3].x, ald[3].y); v1.w = pk2(ald[3].z, ald[3].w);
    *reinterpret_cast<uint4*>(&As[buf][awo0]) = v0;
    *reinterpret_cast<uint4*>(&As[buf][awo1]) = v1;
  };
  auto issueB = [&](int t, int buf) {
#pragma unroll
    for (int j = 0; j < 3; ++j) {
      const u16* src = &hTt[bbase + (long)(j * 64 + brow) * 1536 + t * 64 + bcol];
      gload_lds16(src, &Bs[buf][j * 4096 + w * 512]);   // wave-uniform dest
    }
  };
  auto compute = [&](const u16* Ab, const u16* Bb) {
    __builtin_amdgcn_s_setprio(1);
#pragma unroll
    for (int ks = 0; ks < 2; ++ks) {
      const int ko = (ks * 32 + q * 8) ^ sw;
      bf16x8 a0 = *reinterpret_cast<const bf16x8*>(&Ab[(wm * 32 + lr) * 64 + ko]);
      bf16x8 a1 = *reinterpret_cast<const bf16x8*>(&Ab[(wm * 32 + 16 + lr) * 64 + ko]);
#pragma unroll
      for (int ct = 0; ct < 6; ++ct) {
        bf16x8 bb = *reinterpret_cast<const bf16x8*>(&Bb[(wn * 96 + ct * 16 + lr) * 64 + ko]);
        acc[0][ct] = mfma16(a0, bb, acc[0][ct]);
        acc[1][ct] = mfma16(a1, bb, acc[1][ct]);
      }
    }
    __builtin_amdgcn_s_setprio(0);
  };

  // Prologue: stage tile 0 into buf 0. __syncthreads drains vmcnt+lgkm.
  loadA(0); MEMB;
  issueB(0, 0);
  writeA(0);
  __syncthreads();

  int p = 0;
#pragma unroll 1
  for (int t = 0; t < 24; ++t) {
    if (t < 23) {
      loadA(t + 1); MEMB;      // A fp32 loads (L2-hot after XCD grouping)
      issueB(t + 1, p ^ 1);    // B async direct-to-LDS, drains at the barrier
    }
    compute(As[p], Bs[p]);     // covers the staging latency
    if (t < 23) {
      writeA(p ^ 1);           // compiler waits A-loads only
      __syncthreads();
    }
    p ^= 1;
  }

  // Epilogue: cat[b, sp*2+wn, n0+wm*32+row, 96 + g*96 + d]
  const long cb = (long)((b * 10 + sp * 2 + wn) * 512 + n0 + wm * 32) * 480 + 96 + g * 96;
#pragma unroll
  for (int fr = 0; fr < 2; ++fr) {
#pragma unroll
    for (int ct = 0; ct < 6; ++ct) {
      const int d = ct * 16 + lr;
#pragma unroll
      for (int rg = 0; rg < 4; ++rg) {
        const int row = fr * 16 + q * 4 + rg;
        cat[cb + (long)row * 480 + d] = f2bf(acc[fr][ct][rg]);
      }
    }
  }
}

// ---------------- K3: out = cat @ Wg^T + bias -------------------------------
__global__ __launch_bounds__(256) void k3(const u16* __restrict__ cat,
                                          const float* __restrict__ Wg,
                                          const float* __restrict__ bias,
                                          float* __restrict__ out) {
  __shared__ u16 As[128 * 104];  // cat tile [r=128][c=96] (+8 pad)
  __shared__ u16 Bs[96 * 104];   // Wg rows  [do=96][c=96]
  const int row0 = blockIdx.x * 128;
  const int tid = threadIdx.x;
  const int w = tid >> 6, l = tid & 63;
  const int lr = l & 15, lk = (l >> 4) * 8;
  f32x4 acc[2][6] = {};

  for (int c0 = 0; c0 < 480; c0 += 96) {
#pragma unroll
    for (int i = 0; i < 12; ++i) {
      int idx = tid + i * 256;        // < 3072 = 128*24
      int r = idx / 24, q = idx % 24;
      const ushort4 v = *reinterpret_cast<const ushort4*>(
          &cat[(long)(row0 + r) * 480 + c0 + q * 4]);
      *reinterpret_cast<ushort4*>(&As[r * 104 + q * 4]) = v;
    }
#pragma unroll
    for (int i = 0; i < 9; ++i) {
      int idx = tid + i * 256;        // < 2304 = 96*24
      int j = idx / 24, q = idx % 24;
      const float4 v = *reinterpret_cast<const float4*>(&Wg[j * 480 + c0 + q * 4]);
      uint2 u; u.x = pk2(v.x, v.y); u.y = pk2(v.z, v.w);
      *reinterpret_cast<uint2*>(&Bs[j * 104 + q * 4]) = u;
    }
    __syncthreads();
#pragma unroll
    for (int ks = 0; ks < 3; ++ks) {
      bf16x8 a0 = *reinterpret_cast<const bf16x8*>(&As[(w * 32 + lr) * 104 + ks * 32 + lk]);
      bf16x8 a1 = *reinterpret_cast<const bf16x8*>(&As[(w * 32 + 16 + lr) * 104 + ks * 32 + lk]);
#pragma unroll
      for (int ct = 0; ct < 6; ++ct) {
        bf16x8 bb = *reinterpret_cast<const bf16x8*>(&Bs[(ct * 16 + lr) * 104 + ks * 32 + lk]);
        acc[0][ct] = mfma16(a0, bb, acc[0][ct]);
        acc[1][ct] = mfma16(a1, bb, acc[1][ct]);
      }
    }
    __syncthreads();
  }
#pragma unroll
  for (int rt2 = 0; rt2 < 2; ++rt2) {
    const int r = row0 + w * 32 + rt2 * 16 + (l >> 4) * 4;
#pragma unroll
    for (int ct = 0; ct < 6; ++ct) {
      const int dd = ct * 16 + lr;
      const float bv = bias[dd];
#pragma unroll
      for (int rg = 0; rg < 4; ++rg)
        out[(long)(r + rg) * 96 + dd] = acc[rt2][ct][rg] + bv;
    }
  }
}

extern "C" void kernel_launch(void* const* d_in, const int* in_sizes, int n_in,
                              void* d_out, int out_size, void* d_ws, size_t ws_size,
                              hipStream_t stream) {
  const float* X    = (const float*)d_in[0];
  const float* dyn  = (const float*)d_in[1];
  const float* Wu   = (const float*)d_in[2];
  const float* Wg   = (const float*)d_in[3];
  const float* bias = (const float*)d_in[4];
  float* out = (float*)d_out;

  const size_t hTt_elems = (size_t)160 * 96 * 1536;   // 23,592,960
  const size_t cat_elems = (size_t)81920 * 480;       // 39,321,600
  if (ws_size < (hTt_elems + cat_elems) * sizeof(u16)) return;
  u16* hTt = (u16*)d_ws;
  u16* cat = hTt + hTt_elems;

  hipLaunchKernelGGL(k1,  dim3(3840), dim3(256), 0, stream, X, Wu, hTt);
  hipLaunchKernelGGL(k1b, dim3(640),  dim3(256), 0, stream, hTt, cat);
  hipLaunchKernelGGL(k2,  dim3(1280), dim3(512), 0, stream, dyn, hTt, cat);
  hipLaunchKernelGGL(k3,  dim3(640),  dim3(256), 0, stream, cat, Wg, bias, out);
}